// Round 8
// baseline (1823.301 us; speedup 1.0000x reference)
//
// R8: revert sweep_k -> trsm_k + update_k (parallel grid; sweep was 48us/dispatch
//     due to serial per-stripe row loop). panel v7 (DPP) kept; finalize folded
//     into last panel. Transformer unchanged from R7.
#include <hip/hip_runtime.h>
#include <math.h>
#include <stdint.h>

#define NE 256
#define DD 256
#define NL 2
#define P_TOT 32640          // NE*(NE-1)/2
#define NCHUNK 3
#define PC (P_TOT / NCHUNK)  // 10880 pairs per chunk
#define MC (2 * PC)          // 21760 rows = 170*128
#define MT (MC / 128)        // 170
#define NB 32                // LU panel width
#define NPANEL (NE / NB)

typedef __bf16 bf16x8 __attribute__((ext_vector_type(8)));
typedef float f32x4 __attribute__((ext_vector_type(4)));

__device__ __forceinline__ float bf2f(ushort h) {
    union { unsigned u; float f; } c; c.u = ((unsigned)h) << 16; return c.f;
}
__device__ __forceinline__ ushort f2bf(float f) {
    union { float f; unsigned u; } c; c.f = f;
    unsigned u = c.u;
    return (ushort)((u + 0x7fffu + ((u >> 16) & 1u)) >> 16);
}

#define GLD16(gp, lp) __builtin_amdgcn_global_load_lds( \
    (const __attribute__((address_space(1))) unsigned int*)(uintptr_t)(gp), \
    (__attribute__((address_space(3))) unsigned int*)(uintptr_t)(lp), 16, 0, 0)

// 64-lane max via DPP (VALU-speed): result uniform via readlane(63)
__device__ __forceinline__ unsigned dpp_wave_max(unsigned v) {
    v = max(v, (unsigned)__builtin_amdgcn_update_dpp(0, (int)v, 0x111, 0xF, 0xF, true)); // row_shr:1
    v = max(v, (unsigned)__builtin_amdgcn_update_dpp(0, (int)v, 0x112, 0xF, 0xF, true)); // row_shr:2
    v = max(v, (unsigned)__builtin_amdgcn_update_dpp(0, (int)v, 0x114, 0xF, 0xF, true)); // row_shr:4
    v = max(v, (unsigned)__builtin_amdgcn_update_dpp(0, (int)v, 0x118, 0xF, 0xF, true)); // row_shr:8
    v = max(v, (unsigned)__builtin_amdgcn_update_dpp(0, (int)v, 0x142, 0xF, 0xF, true)); // row_bcast:15
    v = max(v, (unsigned)__builtin_amdgcn_update_dpp(0, (int)v, 0x143, 0xF, 0xF, true)); // row_bcast:31
    return (unsigned)__builtin_amdgcn_readlane((int)v, 63);
}

// ---------------- misc prep: pair indices, acc zero, fused qkv bias ----------------
__global__ void prep_misc_k(int* __restrict__ ip, int* __restrict__ jp, float* __restrict__ acc,
                            const float* __restrict__ bq, const float* __restrict__ bk,
                            const float* __restrict__ bv, float* __restrict__ bqkv) {
    int i = threadIdx.x;  // 0..255
    int base = i * 255 - (i * (i - 1)) / 2;
    for (int j = i + 1; j < NE; ++j) {
        ip[base + j - i - 1] = i;
        jp[base + j - i - 1] = j;
    }
    if (i < 8) acc[i] = 0.f;
    for (int l = 0; l < NL; ++l) {
        bqkv[l * 768 + i] = bq[l * 256 + i];
        bqkv[l * 768 + 256 + i] = bk[l * 256 + i];
        bqkv[l * 768 + 512 + i] = bv[l * 256 + i];
    }
}

__global__ void zero_k(float* __restrict__ p) {
    if (threadIdx.x < 2) p[threadIdx.x] = 0.f;
}

// ---------------- weight prep: Bt[n][k] = W[k][n] in bf16 ----------------
__global__ __launch_bounds__(256) void prep_w_k(
    const float* __restrict__ Wq, const float* __restrict__ Wk, const float* __restrict__ Wv,
    const float* __restrict__ Wo, const float* __restrict__ W1, const float* __restrict__ W2,
    ushort* __restrict__ Wqkv_t, ushort* __restrict__ Woth_t) {
    __shared__ float Ts[32][33];
    int z = blockIdx.z, l = z / 6, m = z % 6;
    const float* src;
    ushort* dst;
    if (m == 0)      { src = Wq + l * 65536; dst = Wqkv_t + (size_t)l * 768 * 256 + 0 * 65536; }
    else if (m == 1) { src = Wk + l * 65536; dst = Wqkv_t + (size_t)l * 768 * 256 + 1 * 65536; }
    else if (m == 2) { src = Wv + l * 65536; dst = Wqkv_t + (size_t)l * 768 * 256 + 2 * 65536; }
    else             { src = (m == 3 ? Wo : m == 4 ? W1 : W2) + l * 65536;
                       dst = Woth_t + (size_t)(l * 3 + (m - 3)) * 65536; }
    int k0 = blockIdx.x * 32, n0 = blockIdx.y * 32;
    int t = threadIdx.x, tr = t >> 5, tc = t & 31;
    for (int i = tr; i < 32; i += 8) Ts[i][tc] = src[(size_t)(k0 + i) * 256 + n0 + tc];
    __syncthreads();
    for (int i = tr; i < 32; i += 8) dst[(size_t)(n0 + i) * 256 + k0 + tc] = f2bf(Ts[tc][i]);
}

// ---------------- embedding: h = feat @ W_in (bf16 out) ----------------
__global__ __launch_bounds__(256) void embed_k(
    const float* __restrict__ el, const float* __restrict__ Win,
    const int* __restrict__ ip, const int* __restrict__ jp,
    ushort* __restrict__ h, int P0) {
    int w = threadIdx.x >> 6, lane = threadIdx.x & 63;
    int r = blockIdx.x * 4 + w;
    int gp = P0 + (r >> 1);
    int e = (r & 1) ? jp[gp] : ip[gp];
    float th = el[2 * e], ph = el[2 * e + 1];
    float st = sinf(th);
    float f0 = cosf(th), f1 = st * cosf(ph), f2 = st * sinf(ph);
    int n = lane * 4;
    float4 w0 = *(const float4*)&Win[n];
    float4 w1 = *(const float4*)&Win[256 + n];
    float4 w2 = *(const float4*)&Win[512 + n];
    ushort4 o;
    o.x = f2bf(f0 * w0.x + f1 * w1.x + f2 * w2.x);
    o.y = f2bf(f0 * w0.y + f1 * w1.y + f2 * w2.y);
    o.z = f2bf(f0 * w0.z + f1 * w1.z + f2 * w2.z);
    o.w = f2bf(f0 * w0.w + f1 * w1.w + f2 * w2.w);
    *(ushort4*)&h[(size_t)r * 256 + n] = o;
}

// ---------------- bf16 MFMA GEMM (128x128 tile, 256t): C = A@B (+bias) ----------------
template <bool BIAS>
__global__ __launch_bounds__(256) void gemm_k(
    const ushort* __restrict__ A, int lda,
    const ushort* __restrict__ Bt,
    const float* __restrict__ bias,
    ushort* __restrict__ C, int ldc) {
    __shared__ ushort As[128 * 64];
    __shared__ ushort Bs[128 * 64];
    int t = threadIdx.x, lane = t & 63, w = t >> 6;
    int row0 = blockIdx.x * 128, col0 = blockIdx.y * 128;
    int lrow = lane >> 3;
    int kx = ((lane & 7) ^ lrow) << 3;
    const ushort* gA = A + (size_t)(row0 + w * 32 + lrow) * lda + kx;
    const ushort* gB = Bt + (size_t)(col0 + w * 32 + lrow) * 256 + kx;
    f32x4 acc[4][4];
#pragma unroll
    for (int i = 0; i < 4; ++i)
#pragma unroll
        for (int j = 0; j < 4; ++j) acc[i][j] = (f32x4){0.f, 0.f, 0.f, 0.f};
    int wm = w >> 1, wn = w & 1;
    int mbase = wm * 64 + (lane & 15);
    int nbase = wn * 64 + (lane & 15);
    int l7 = lane & 7;
    for (int k0 = 0; k0 < 256; k0 += 64) {
        __syncthreads();
#pragma unroll
        for (int c2 = 0; c2 < 4; ++c2) {
            GLD16(gA + (size_t)(c2 * 8) * lda + k0, &As[(w * 4 + c2) * 512]);
            GLD16(gB + (size_t)(c2 * 8) * 256 + k0, &Bs[(w * 4 + c2) * 512]);
        }
        __syncthreads();
#pragma unroll
        for (int ks = 0; ks < 2; ++ks) {
            int kb = ks * 4 + (lane >> 4);
            bf16x8 af[4], bfr[4];
#pragma unroll
            for (int tm = 0; tm < 4; ++tm)
                af[tm] = *(const bf16x8*)&As[(mbase + tm * 16) * 64 + ((kb ^ l7) << 3)];
#pragma unroll
            for (int tn = 0; tn < 4; ++tn)
                bfr[tn] = *(const bf16x8*)&Bs[(nbase + tn * 16) * 64 + ((kb ^ l7) << 3)];
#pragma unroll
            for (int tm = 0; tm < 4; ++tm)
#pragma unroll
                for (int tn = 0; tn < 4; ++tn)
                    acc[tm][tn] = __builtin_amdgcn_mfma_f32_16x16x32_bf16(
                        af[tm], bfr[tn], acc[tm][tn], 0, 0, 0);
        }
    }
    int q = lane >> 4;
    int crow = row0 + wm * 64 + q * 4;
    int ccol = col0 + wn * 64 + (lane & 15);
#pragma unroll
    for (int tm = 0; tm < 4; ++tm)
#pragma unroll
        for (int r = 0; r < 4; ++r) {
            int row = crow + tm * 16 + r;
#pragma unroll
            for (int tn = 0; tn < 4; ++tn) {
                int col = ccol + tn * 16;
                float v = acc[tm][tn][r];
                if (BIAS) v += bias[col];
                C[(size_t)row * ldc + col] = f2bf(v);
            }
        }
}

// ---------------- fused GEMM + LayerNorm epilogue (128x256 tile, N=K=256) ----------
// VARIANT 0: out = LN(A@B + R)                (post-W1; R = residual, no bias)
// VARIANT 1: out = LN(A + tanh(A@B + bias))   (post-W2; A re-read as residual)
template <int VARIANT>
__global__ __launch_bounds__(256) void gemm_ln_k(
    const ushort* __restrict__ A, int lda,
    const ushort* __restrict__ Bt,
    const float* __restrict__ bias,
    const ushort* __restrict__ Rm,
    const float* __restrict__ sc, const float* __restrict__ bi,
    ushort* __restrict__ C) {
    __shared__ union {
        struct { ushort As[128 * 64]; ushort Bs[256 * 64]; } s;           // 48 KB
        struct { char pad[128 * 64 * 2]; float part[128][2][17][2]; } r;  // part overlays Bs
    } u;
    __shared__ float mv[128][2];
    int t = threadIdx.x, lane = t & 63, w = t >> 6;
    int row0 = blockIdx.x * 128;
    int lrow = lane >> 3;
    int kx = ((lane & 7) ^ lrow) << 3;
    const ushort* gA = A + (size_t)(row0 + w * 32 + lrow) * lda + kx;
    const ushort* gB = Bt + (size_t)(w * 64 + lrow) * 256 + kx;
    f32x4 acc[4][8];
#pragma unroll
    for (int i = 0; i < 4; ++i)
#pragma unroll
        for (int j = 0; j < 8; ++j) acc[i][j] = (f32x4){0.f, 0.f, 0.f, 0.f};
    int wm = w >> 1, wn = w & 1;
    int mbase = wm * 64 + (lane & 15);
    int nbase = wn * 128 + (lane & 15);
    int l7 = lane & 7;
    for (int k0 = 0; k0 < 256; k0 += 64) {
        __syncthreads();
#pragma unroll
        for (int c2 = 0; c2 < 4; ++c2)
            GLD16(gA + (size_t)(c2 * 8) * lda + k0, &u.s.As[(w * 4 + c2) * 512]);
#pragma unroll
        for (int c2 = 0; c2 < 8; ++c2)
            GLD16(gB + (size_t)(c2 * 8) * 256 + k0, &u.s.Bs[(w * 8 + c2) * 512]);
        __syncthreads();
#pragma unroll
        for (int ks = 0; ks < 2; ++ks) {
            int kb = ks * 4 + (lane >> 4);
            bf16x8 af[4], bfr[8];
#pragma unroll
            for (int tm = 0; tm < 4; ++tm)
                af[tm] = *(const bf16x8*)&u.s.As[(mbase + tm * 16) * 64 + ((kb ^ l7) << 3)];
#pragma unroll
            for (int tn = 0; tn < 8; ++tn)
                bfr[tn] = *(const bf16x8*)&u.s.Bs[(nbase + tn * 16) * 64 + ((kb ^ l7) << 3)];
#pragma unroll
            for (int tm = 0; tm < 4; ++tm)
#pragma unroll
                for (int tn = 0; tn < 8; ++tn)
                    acc[tm][tn] = __builtin_amdgcn_mfma_f32_16x16x32_bf16(
                        af[tm], bfr[tn], acc[tm][tn], 0, 0, 0);
        }
    }
    int q = lane >> 4, l15 = lane & 15;
    float bcol[8], scol[8], bicol[8];
#pragma unroll
    for (int tn = 0; tn < 8; ++tn) {
        int col = wn * 128 + tn * 16 + l15;
        bcol[tn] = (VARIANT == 1) ? bias[col] : 0.f;
        scol[tn] = sc[col];
        bicol[tn] = bi[col];
    }
    __syncthreads();  // done with As/Bs; part overlay begins
#pragma unroll
    for (int tm = 0; tm < 4; ++tm)
#pragma unroll
        for (int r = 0; r < 4; ++r) {
            int row_l = wm * 64 + tm * 16 + q * 4 + r;
            int row = row0 + row_l;
            float sum = 0.f, sq = 0.f;
#pragma unroll
            for (int tn = 0; tn < 8; ++tn) {
                int col = wn * 128 + tn * 16 + l15;
                float v = acc[tm][tn][r];
                if (VARIANT == 0) {
                    v += bf2f(Rm[(size_t)row * 256 + col]);
                } else {
                    v = bf2f(A[(size_t)row * lda + col]) + tanhf(v + bcol[tn]);
                }
                acc[tm][tn][r] = v;
                sum += v;
                sq += v * v;
            }
            *(float2*)&u.r.part[row_l][wn][l15][0] = make_float2(sum, sq);
        }
    __syncthreads();
    {
        int row = t >> 1, half = t & 1;
        float sum = 0.f, sq = 0.f;
#pragma unroll
        for (int i = 0; i < 16; ++i) {
            float2 pp = *(const float2*)&u.r.part[row][half][i][0];
            sum += pp.x;
            sq += pp.y;
        }
        sum += __shfl_xor(sum, 1, 64);
        sq += __shfl_xor(sq, 1, 64);
        if (half == 0) {
            float m = sum * (1.f / 256.f);
            float var = sq * (1.f / 256.f) - m * m;
            mv[row][0] = m;
            mv[row][1] = rsqrtf(var + 1e-5f);
        }
    }
    __syncthreads();
#pragma unroll
    for (int tm = 0; tm < 4; ++tm)
#pragma unroll
        for (int r = 0; r < 4; ++r) {
            int row_l = wm * 64 + tm * 16 + q * 4 + r;
            int row = row0 + row_l;
            float m = mv[row_l][0], rs = mv[row_l][1];
#pragma unroll
            for (int tn = 0; tn < 8; ++tn) {
                int col = wn * 128 + tn * 16 + l15;
                float v = (acc[tm][tn][r] - m) * rs * scol[tn] + bicol[tn];
                C[(size_t)row * 256 + col] = f2bf(v);
            }
        }
}

// ---------------- attention (seq=2) on fused qkv [row,768] ----------------
__global__ __launch_bounds__(256) void attn_k(ushort* __restrict__ qkv) {
    int wid = threadIdx.x >> 6, lane = threadIdx.x & 63;
    int gw = blockIdx.x * 4 + wid;
    int p = gw >> 2, hh = gw & 3;
    size_t r0 = (size_t)(2 * p) * 768 + hh * 64 + lane;
    size_t r1 = r0 + 768;
    float q0 = bf2f(qkv[r0]) * 0.125f, q1 = bf2f(qkv[r1]) * 0.125f;
    float k0 = bf2f(qkv[r0 + 256]), k1 = bf2f(qkv[r1 + 256]);
    float v0 = bf2f(qkv[r0 + 512]), v1 = bf2f(qkv[r1 + 512]);
    float s00 = q0 * k0, s01 = q0 * k1, s10 = q1 * k0, s11 = q1 * k1;
#pragma unroll
    for (int off = 32; off; off >>= 1) {
        s00 += __shfl_xor(s00, off, 64);
        s01 += __shfl_xor(s01, off, 64);
        s10 += __shfl_xor(s10, off, 64);
        s11 += __shfl_xor(s11, off, 64);
    }
    float m0 = fmaxf(s00, s01), m1 = fmaxf(s10, s11);
    float e00 = expf(s00 - m0), e01 = expf(s01 - m0);
    float e10 = expf(s10 - m1), e11 = expf(s11 - m1);
    float i0 = 1.f / (e00 + e01), i1 = 1.f / (e10 + e11);
    float o0 = (e00 * i0) * v0 + (e01 * i0) * v1;
    float o1 = (e10 * i1) * v0 + (e11 * i1) * v1;
    qkv[r0] = f2bf(o0);
    qkv[r1] = f2bf(o1);
}

// ---------------- per-pair orbitals + 2x2 det ----------------
__global__ __launch_bounds__(256) void orb_k(
    const ushort* __restrict__ h, const float* __restrict__ Wr, const float* __restrict__ Wi,
    const float* __restrict__ el, const int* __restrict__ ip, const int* __restrict__ jp,
    float2* __restrict__ porb, int P0) {
    int w = threadIdx.x >> 6, lane = threadIdx.x & 63;
    int p = blockIdx.x * 4 + w;
    const ushort* h0 = h + (size_t)(2 * p) * 256;
    int d0 = lane * 4;
    ushort4 a0 = *(const ushort4*)&h0[d0];
    ushort4 a1 = *(const ushort4*)&h0[256 + d0];
    float x0[4] = {bf2f(a0.x), bf2f(a0.y), bf2f(a0.z), bf2f(a0.w)};
    float x1[4] = {bf2f(a1.x), bf2f(a1.y), bf2f(a1.z), bf2f(a1.w)};
    float wrv[8], wiv[8];
    *(float4*)&wrv[0] = *(const float4*)&Wr[2 * d0];
    *(float4*)&wrv[4] = *(const float4*)&Wr[2 * d0 + 4];
    *(float4*)&wiv[0] = *(const float4*)&Wi[2 * d0];
    *(float4*)&wiv[4] = *(const float4*)&Wi[2 * d0 + 4];
    float s[8] = {0, 0, 0, 0, 0, 0, 0, 0};
#pragma unroll
    for (int u = 0; u < 4; ++u) {
        s[0] += x0[u] * wrv[2 * u];     s[1] += x0[u] * wiv[2 * u];
        s[2] += x0[u] * wrv[2 * u + 1]; s[3] += x0[u] * wiv[2 * u + 1];
        s[4] += x1[u] * wrv[2 * u];     s[5] += x1[u] * wiv[2 * u];
        s[6] += x1[u] * wrv[2 * u + 1]; s[7] += x1[u] * wiv[2 * u + 1];
    }
#pragma unroll
    for (int off = 32; off; off >>= 1) {
#pragma unroll
        for (int q2 = 0; q2 < 8; ++q2) s[q2] += __shfl_xor(s[q2], off, 64);
    }
    if (lane == 0) {
        int gp = P0 + p;
        int i = ip[gp], j = jp[gp];
        float thi = el[2 * i], phi_ = el[2 * i + 1];
        float thj = el[2 * j], phj = el[2 * j + 1];
        float chi = cosf(thi * 0.5f), shi = sinf(thi * 0.5f);
        float chj = cosf(thj * 0.5f), shj = sinf(thj * 0.5f);
        float cpi = cosf(phi_ * 0.5f), spi = sinf(phi_ * 0.5f);
        float cpj = cosf(phj * 0.5f), spj = sinf(phj * 0.5f);
        float uix = chi * cpi, uiy = chi * spi;
        float vix = shi * cpi, viy = -shi * spi;
        float ujx = chj * cpj, ujy = chj * spj;
        float vjx = shj * cpj, vjy = -shj * spj;
        float crx = (uix * vjx - uiy * vjy) - (ujx * vix - ujy * viy);
        float cry = (uix * vjy + uiy * vjx) - (ujx * viy + ujy * vix);
        float chord2 = crx * crx + cry * cry;
        float trunc = 1.f - expf(-100.f * chord2);
        float t2 = trunc * trunc;
        float dr = (s[0] * s[6] - s[1] * s[7]) - (s[2] * s[4] - s[3] * s[5]);
        float di = (s[0] * s[7] + s[1] * s[6]) - (s[2] * s[5] + s[3] * s[4]);
        porb[gp] = make_float2(dr * t2, di * t2);
    }
}

// ---------------- assemble A = pf + cusp, accumulate log_bos ----------------
__global__ __launch_bounds__(256) void assemble_k(
    const float* __restrict__ el, const float2* __restrict__ porb,
    float2* __restrict__ Am, float* acc) {
    __shared__ float sre[256], sim[256];
    int idx = blockIdx.x * 256 + threadIdx.x;
    int i = idx >> 8, j = idx & 255;
    float thi = el[2 * i], phi_ = el[2 * i + 1];
    float thj = el[2 * j], phj = el[2 * j + 1];
    float chi = cosf(thi * 0.5f), shi = sinf(thi * 0.5f);
    float chj = cosf(thj * 0.5f), shj = sinf(thj * 0.5f);
    float cpi = cosf(phi_ * 0.5f), spi = sinf(phi_ * 0.5f);
    float cpj = cosf(phj * 0.5f), spj = sinf(phj * 0.5f);
    float uix = chi * cpi, uiy = chi * spi;
    float vix = shi * cpi, viy = -shi * spi;
    float ujx = chj * cpj, ujy = chj * spj;
    float vjx = shj * cpj, vjy = -shj * spj;
    float ex = (uix * vjx - uiy * vjy) - (ujx * vix - ujy * viy);
    float ey = (uix * vjy + uiy * vjx) - (ujx * viy + ujy * vix);
    float pfx = 0.f, pfy = 0.f;
    if (i < j) {
        int pp = i * 255 - (i * (i - 1)) / 2 + (j - i - 1);
        float2 t = porb[pp]; pfx = t.x; pfy = t.y;
    } else if (i > j) {
        int pp = j * 255 - (j * (j - 1)) / 2 + (i - j - 1);
        float2 t = porb[pp]; pfx = -t.x; pfy = -t.y;
    }
    float eye = (i == j) ? 1.f : 0.f;
    float ecx = ex + eye, ecy = ey;
    float wgt = expf(-100.f * (ecx * ecx + ecy * ecy));
    Am[idx] = make_float2(pfx + ecx * wgt, pfy + ecy * wgt);
    float lre = 0.f, lim = 0.f;
    if (i != j) {
        float r2 = ex * ex + ey * ey;
        lre = 0.5f * logf(0.01f + r2);
        lim = atan2f(ey, ex);
    }
    sre[threadIdx.x] = lre; sim[threadIdx.x] = lim;
    __syncthreads();
    for (int s2 = 128; s2; s2 >>= 1) {
        if (threadIdx.x < s2) {
            sre[threadIdx.x] += sre[threadIdx.x + s2];
            sim[threadIdx.x] += sim[threadIdx.x + s2];
        }
        __syncthreads();
    }
    if (threadIdx.x == 0) {
        atomicAdd(acc + 0, sre[0]);
        atomicAdd(acc + 1, sim[0]);
    }
}

// ---------------- LU panel v7: register rows + DPP argmax (+ last-panel finalize) ----
__global__ __launch_bounds__(256, 1) void panel_k(
    float2* __restrict__ Am, int* __restrict__ pivg, float* __restrict__ acc, int k0,
    float* __restrict__ out) {
    __shared__ unsigned wmax[4];
    __shared__ float2 urow_s[NB];
    __shared__ float2 rowj_s[NB];
    __shared__ float2 diag_s[NB];
    int t = threadIdx.x, lane = t & 63, w = t >> 6;
    int nr = NE - k0;
    bool act = t < nr;
    float2 a[NB];
    if (act) {
        const float2* src = Am + (size_t)(k0 + t) * NE + k0;
#pragma unroll
        for (int c = 0; c < NB; ++c) a[c] = src[c];
    }
    unsigned key = 0u;
    if (act) {
        float v = fabsf(a[0].x) + fabsf(a[0].y);
        key = (__float_as_uint(v) & 0xFFFFFF00u) | (unsigned)t;
    }
    int nsw = 0;
#pragma unroll
    for (int j = 0; j < NB; ++j) {
        unsigned mk = dpp_wave_max(key);   // VALU-speed, uniform per wave
        if (lane == 0) wmax[w] = mk;
        __syncthreads();
        mk = max(max(wmax[0], wmax[1]), max(wmax[2], wmax[3]));
        int piv = (int)(mk & 0xFFu);
        if (t == piv) {
#pragma unroll
            for (int c = 0; c < NB; ++c) urow_s[c] = a[c];
        }
        if (t == j && j != piv) {
#pragma unroll
            for (int c = 0; c < NB; ++c) rowj_s[c] = a[c];
        }
        if (t == 0) {
            pivg[j] = k0 + piv;
            if (piv != j) nsw++;
        }
        __syncthreads();
        float2 uu[NB];
#pragma unroll
        for (int c = j; c < NB; ++c) uu[c] = urow_s[c];
        float2 d = uu[j];
        if (t == 0) diag_s[j] = d;
        float ivn = 1.f / (d.x * d.x + d.y * d.y);
        float2 inv = make_float2(d.x * ivn, -d.y * ivn);
        if (t == j) {
#pragma unroll
            for (int c = j; c < NB; ++c) a[c] = uu[c];
#pragma unroll
            for (int c = 0; c < j; ++c) a[c] = urow_s[c];
        } else if (t == piv) {
#pragma unroll
            for (int c = 0; c < NB; ++c) a[c] = rowj_s[c];
        }
        key = 0u;
        if (act && t > j) {
            float2 L = make_float2(a[j].x * inv.x - a[j].y * inv.y,
                                   a[j].x * inv.y + a[j].y * inv.x);
            a[j] = L;
#pragma unroll
            for (int c = j + 1; c < NB; ++c) {
                a[c].x -= L.x * uu[c].x - L.y * uu[c].y;
                a[c].y -= L.x * uu[c].y + L.y * uu[c].x;
            }
            if (j + 1 < NB) {
                float v = fabsf(a[j + 1].x) + fabsf(a[j + 1].y);
                key = (__float_as_uint(v) & 0xFFFFFF00u) | (unsigned)t;
            }
        }
    }
    if (act) {
        float2* dst = Am + (size_t)(k0 + t) * NE + k0;
#pragma unroll
        for (int c = 0; c < NB; ++c) dst[c] = a[c];
    }
    __syncthreads();
    if (w == 0) {
        float lre = 0.f, lim = 0.f;
        if (lane < NB) {
            float2 d = diag_s[lane];
            lre = 0.5f * logf(d.x * d.x + d.y * d.y);
            lim = atan2f(d.y, d.x);
        }
#pragma unroll
        for (int off = 32; off; off >>= 1) {
            lre += __shfl_xor(lre, off, 64);
            lim += __shfl_xor(lim, off, 64);
        }
        if (lane == 0) {
            float l2 = acc[2] + lre, l3 = acc[3] + lim;
            acc[2] = l2; acc[3] = l3;
            if (out) {  // last panel: finalize here (t==0 path; acc[4] updated below first)
                float l4 = acc[4] + (float)nsw;
                acc[4] = l4;
                float ang = l3 + 3.14159265358979323846f * l4;
                ang -= 6.283185307179586f * rintf(ang * 0.15915494309189535f);
                out[0] = 0.5f * l2 + acc[0];
                out[1] = 0.5f * ang + acc[1];
            }
        }
    }
    if (t == 0 && !out) acc[4] += (float)nsw;
}

// ---------------- trsm: composed-permutation gather + register solve ----------------
__global__ __launch_bounds__(256) void trsm_k(
    float2* __restrict__ Am, const int* __restrict__ pivg, int k0) {
    __shared__ float2 Ls[NB][NB + 1];
    __shared__ short sigma[NE];
    __shared__ short rlist[NB];
    __shared__ int rcount;
    int t = threadIdx.x;
    for (int idx = t; idx < NB * NB; idx += 256)
        Ls[idx >> 5][idx & 31] = Am[(size_t)(k0 + (idx >> 5)) * NE + k0 + (idx & 31)];
    {   // parallel sigma: replay swaps backward on own index
        int x = t;
#pragma unroll
        for (int j = NB - 1; j >= 0; --j) {
            int pj = pivg[j], rj = k0 + j;
            x = (x == rj) ? pj : ((x == pj) ? rj : x);
        }
        sigma[t] = (short)x;
    }
    if (t < NB) rlist[t] = (short)k0;  // dummy default (valid row, never stored)
    if (t == 0) rcount = 0;
    __syncthreads();
    if (t >= k0 + NB && sigma[t] != t) {
        int s = atomicAdd(&rcount, 1);
        rlist[s] = (short)t;
    }
    __syncthreads();
    int ncols = NE - k0 - NB;
    if (t >= ncols) return;
    int col = k0 + NB + t;
    int cnt = rcount;
    float2 x[NB];
#pragma unroll
    for (int i = 0; i < NB; ++i)
        x[i] = Am[(size_t)sigma[k0 + i] * NE + col];
    float2 extra[NB];
#pragma unroll
    for (int q = 0; q < NB; ++q)
        extra[q] = Am[(size_t)sigma[rlist[q]] * NE + col];
#pragma unroll
    for (int i = 1; i < NB; ++i) {
        float2 xi = x[i];
#pragma unroll
        for (int j = 0; j < i; ++j) {
            float2 l = Ls[i][j];
            xi.x -= l.x * x[j].x - l.y * x[j].y;
            xi.y -= l.x * x[j].y + l.y * x[j].x;
        }
        x[i] = xi;
    }
#pragma unroll
    for (int i = 0; i < NB; ++i)
        Am[(size_t)(k0 + i) * NE + col] = x[i];
#pragma unroll
    for (int q = 0; q < NB; ++q)
        if (q < cnt) Am[(size_t)rlist[q] * NE + col] = extra[q];
}

// A22 -= L21 @ U12, complex, K=NB. 32x32 tile per block.
__global__ __launch_bounds__(256) void update_k(float2* __restrict__ Am, int k0) {
    __shared__ float2 Lt[NB][NB + 1];
    __shared__ float2 Ut[NB][NB + 1];
    int t = threadIdx.x;
    int r0 = k0 + NB + blockIdx.x * NB;
    int c0 = k0 + NB + blockIdx.y * NB;
    for (int idx = t; idx < NB * NB; idx += 256) {
        int a = idx >> 5, b = idx & 31;
        Lt[a][b] = Am[(size_t)(r0 + a) * NE + k0 + b];
        Ut[a][b] = Am[(size_t)(k0 + a) * NE + c0 + b];
    }
    __syncthreads();
    int lr = t >> 3, lc0 = (t & 7) * 4;
    float2 s0 = {0.f, 0.f}, s1 = {0.f, 0.f}, s2 = {0.f, 0.f}, s3 = {0.f, 0.f};
#pragma unroll
    for (int k = 0; k < NB; ++k) {
        float2 a = Lt[lr][k];
        float2 u0 = Ut[k][lc0 + 0], u1 = Ut[k][lc0 + 1];
        float2 u2 = Ut[k][lc0 + 2], u3 = Ut[k][lc0 + 3];
        s0.x += a.x * u0.x - a.y * u0.y; s0.y += a.x * u0.y + a.y * u0.x;
        s1.x += a.x * u1.x - a.y * u1.y; s1.y += a.x * u1.y + a.y * u1.x;
        s2.x += a.x * u2.x - a.y * u2.y; s2.y += a.x * u2.y + a.y * u2.x;
        s3.x += a.x * u3.x - a.y * u3.y; s3.y += a.x * u3.y + a.y * u3.x;
    }
    size_t base = (size_t)(r0 + lr) * NE + c0 + lc0;
    float2 cc;
    cc = Am[base + 0]; cc.x -= s0.x; cc.y -= s0.y; Am[base + 0] = cc;
    cc = Am[base + 1]; cc.x -= s1.x; cc.y -= s1.y; Am[base + 1] = cc;
    cc = Am[base + 2]; cc.x -= s2.x; cc.y -= s2.y; Am[base + 2] = cc;
    cc = Am[base + 3]; cc.x -= s3.x; cc.y -= s3.y; Am[base + 3] = cc;
}

// ---------------- host launch ----------------
extern "C" void kernel_launch(void* const* d_in, const int* in_sizes, int n_in,
                              void* d_out, int out_size, void* d_ws, size_t ws_size,
                              hipStream_t stream) {
    (void)in_sizes; (void)n_in; (void)out_size;
    const float* el   = (const float*)d_in[0];
    const float* Win  = (const float*)d_in[1];
    const float* Wq   = (const float*)d_in[2];
    const float* bq   = (const float*)d_in[3];
    const float* Wk   = (const float*)d_in[4];
    const float* bk   = (const float*)d_in[5];
    const float* Wv   = (const float*)d_in[6];
    const float* bv   = (const float*)d_in[7];
    const float* Wo   = (const float*)d_in[8];
    const float* bo   = (const float*)d_in[9];
    const float* W1   = (const float*)d_in[10];
    const float* ln1s = (const float*)d_in[11];
    const float* ln1b = (const float*)d_in[12];
    const float* W2   = (const float*)d_in[13];
    const float* b2   = (const float*)d_in[14];
    const float* ln2s = (const float*)d_in[15];
    const float* ln2b = (const float*)d_in[16];
    const float* Wor  = (const float*)d_in[17];
    const float* Woi  = (const float*)d_in[18];

    char* wp = (char*)d_ws;
    auto alloc = [&](size_t b) {
        char* r = wp;
        wp += (b + 255) & ~(size_t)255;
        return r;
    };
    int*    ipb  = (int*)alloc((size_t)P_TOT * 4);
    int*    jpb  = (int*)alloc((size_t)P_TOT * 4);
    float2* porb = (float2*)alloc((size_t)P_TOT * 8);
    float2* Am   = (float2*)alloc((size_t)NE * NE * 8);
    float*  acc  = (float*)alloc(256);
    int*    pivg = (int*)alloc((size_t)NE * 4);
    ushort* Wqkv_t = (ushort*)alloc((size_t)2 * 768 * 256 * 2);
    ushort* Woth_t = (ushort*)alloc((size_t)6 * 65536 * 2);
    float*  bqkv = (float*)alloc((size_t)2 * 768 * 4);
    ushort* hb   = (ushort*)alloc((size_t)MC * 256 * 2);
    ushort* qkvb = (ushort*)alloc((size_t)MC * 768 * 2);
    ushort* tb   = (ushort*)alloc((size_t)MC * 256 * 2);
    size_t need = (size_t)(wp - (char*)d_ws);
    if (need > ws_size) {
        zero_k<<<1, 64, 0, stream>>>((float*)d_out);
        return;
    }

    prep_w_k<<<dim3(8, 8, 12), 256, 0, stream>>>(Wq, Wk, Wv, Wo, W1, W2, Wqkv_t, Woth_t);
    prep_misc_k<<<1, 256, 0, stream>>>(ipb, jpb, acc, bq, bk, bv, bqkv);

    for (int c = 0; c < NCHUNK; ++c) {
        int P0 = c * PC;
        embed_k<<<MC / 4, 256, 0, stream>>>(el, Win, ipb, jpb, hb, P0);
        for (int l = 0; l < NL; ++l) {
            gemm_k<true><<<dim3(MT, 6), 256, 0, stream>>>(
                hb, 256, Wqkv_t + (size_t)l * 768 * 256, bqkv + l * 768, qkvb, 768);
            attn_k<<<PC, 256, 0, stream>>>(qkvb);
            gemm_k<true><<<dim3(MT, 2), 256, 0, stream>>>(
                qkvb, 768, Woth_t + (size_t)(l * 3 + 0) * 65536, bo + l * 256, tb, 256);
            gemm_ln_k<0><<<MT, 256, 0, stream>>>(
                tb, 256, Woth_t + (size_t)(l * 3 + 1) * 65536, nullptr, hb,
                ln1s + l * 256, ln1b + l * 256, hb);
            gemm_ln_k<1><<<MT, 256, 0, stream>>>(
                hb, 256, Woth_t + (size_t)(l * 3 + 2) * 65536, b2 + l * 256, nullptr,
                ln2s + l * 256, ln2b + l * 256, hb);
        }
        orb_k<<<PC / 4, 256, 0, stream>>>(hb, Wor, Woi, el, ipb, jpb, porb, P0);
    }
    assemble_k<<<NE, 256, 0, stream>>>(el, porb, Am, acc);

    for (int p = 0; p < NPANEL; ++p) {
        int k0 = p * NB;
        float* outp = (p == NPANEL - 1) ? (float*)d_out : nullptr;
        panel_k<<<1, 256, 0, stream>>>(Am, pivg + p * NB, acc, k0, outp);
        int m = NE - k0 - NB;
        if (m > 0) {
            trsm_k<<<1, 256, 0, stream>>>(Am, pivg + p * NB, k0);
            dim3 ug(m / NB, m / NB);
            update_k<<<ug, 256, 0, stream>>>(Am, k0);
        }
    }
}

// Round 9
// 1237.614 us; speedup vs baseline: 1.4732x; 1.4732x over previous
//
// R9: single-variable revert — panel_k restored to EXACT R7 code (4 args; the R8
//     out-param/finalize fold tipped codegen into scratch spill: 47->127us),
//     finalize_k separate again. LU tail = trsm_k + update_k (R8). Transformer = R7.
#include <hip/hip_runtime.h>
#include <math.h>
#include <stdint.h>

#define NE 256
#define DD 256
#define NL 2
#define P_TOT 32640          // NE*(NE-1)/2
#define NCHUNK 3
#define PC (P_TOT / NCHUNK)  // 10880 pairs per chunk
#define MC (2 * PC)          // 21760 rows = 170*128
#define MT (MC / 128)        // 170
#define NB 32                // LU panel width
#define NPANEL (NE / NB)

typedef __bf16 bf16x8 __attribute__((ext_vector_type(8)));
typedef float f32x4 __attribute__((ext_vector_type(4)));

__device__ __forceinline__ float bf2f(ushort h) {
    union { unsigned u; float f; } c; c.u = ((unsigned)h) << 16; return c.f;
}
__device__ __forceinline__ ushort f2bf(float f) {
    union { float f; unsigned u; } c; c.f = f;
    unsigned u = c.u;
    return (ushort)((u + 0x7fffu + ((u >> 16) & 1u)) >> 16);
}

#define GLD16(gp, lp) __builtin_amdgcn_global_load_lds( \
    (const __attribute__((address_space(1))) unsigned int*)(uintptr_t)(gp), \
    (__attribute__((address_space(3))) unsigned int*)(uintptr_t)(lp), 16, 0, 0)

// 64-lane max via DPP (VALU-speed): result uniform via readlane(63)
__device__ __forceinline__ unsigned dpp_wave_max(unsigned v) {
    v = max(v, (unsigned)__builtin_amdgcn_update_dpp(0, (int)v, 0x111, 0xF, 0xF, true)); // row_shr:1
    v = max(v, (unsigned)__builtin_amdgcn_update_dpp(0, (int)v, 0x112, 0xF, 0xF, true)); // row_shr:2
    v = max(v, (unsigned)__builtin_amdgcn_update_dpp(0, (int)v, 0x114, 0xF, 0xF, true)); // row_shr:4
    v = max(v, (unsigned)__builtin_amdgcn_update_dpp(0, (int)v, 0x118, 0xF, 0xF, true)); // row_shr:8
    v = max(v, (unsigned)__builtin_amdgcn_update_dpp(0, (int)v, 0x142, 0xF, 0xF, true)); // row_bcast:15
    v = max(v, (unsigned)__builtin_amdgcn_update_dpp(0, (int)v, 0x143, 0xF, 0xF, true)); // row_bcast:31
    return (unsigned)__builtin_amdgcn_readlane((int)v, 63);
}

// ---------------- misc prep: pair indices, acc zero, fused qkv bias ----------------
__global__ void prep_misc_k(int* __restrict__ ip, int* __restrict__ jp, float* __restrict__ acc,
                            const float* __restrict__ bq, const float* __restrict__ bk,
                            const float* __restrict__ bv, float* __restrict__ bqkv) {
    int i = threadIdx.x;  // 0..255
    int base = i * 255 - (i * (i - 1)) / 2;
    for (int j = i + 1; j < NE; ++j) {
        ip[base + j - i - 1] = i;
        jp[base + j - i - 1] = j;
    }
    if (i < 8) acc[i] = 0.f;
    for (int l = 0; l < NL; ++l) {
        bqkv[l * 768 + i] = bq[l * 256 + i];
        bqkv[l * 768 + 256 + i] = bk[l * 256 + i];
        bqkv[l * 768 + 512 + i] = bv[l * 256 + i];
    }
}

__global__ void zero_k(float* __restrict__ p) {
    if (threadIdx.x < 2) p[threadIdx.x] = 0.f;
}

// ---------------- weight prep: Bt[n][k] = W[k][n] in bf16 ----------------
__global__ __launch_bounds__(256) void prep_w_k(
    const float* __restrict__ Wq, const float* __restrict__ Wk, const float* __restrict__ Wv,
    const float* __restrict__ Wo, const float* __restrict__ W1, const float* __restrict__ W2,
    ushort* __restrict__ Wqkv_t, ushort* __restrict__ Woth_t) {
    __shared__ float Ts[32][33];
    int z = blockIdx.z, l = z / 6, m = z % 6;
    const float* src;
    ushort* dst;
    if (m == 0)      { src = Wq + l * 65536; dst = Wqkv_t + (size_t)l * 768 * 256 + 0 * 65536; }
    else if (m == 1) { src = Wk + l * 65536; dst = Wqkv_t + (size_t)l * 768 * 256 + 1 * 65536; }
    else if (m == 2) { src = Wv + l * 65536; dst = Wqkv_t + (size_t)l * 768 * 256 + 2 * 65536; }
    else             { src = (m == 3 ? Wo : m == 4 ? W1 : W2) + l * 65536;
                       dst = Woth_t + (size_t)(l * 3 + (m - 3)) * 65536; }
    int k0 = blockIdx.x * 32, n0 = blockIdx.y * 32;
    int t = threadIdx.x, tr = t >> 5, tc = t & 31;
    for (int i = tr; i < 32; i += 8) Ts[i][tc] = src[(size_t)(k0 + i) * 256 + n0 + tc];
    __syncthreads();
    for (int i = tr; i < 32; i += 8) dst[(size_t)(n0 + i) * 256 + k0 + tc] = f2bf(Ts[tc][i]);
}

// ---------------- embedding: h = feat @ W_in (bf16 out) ----------------
__global__ __launch_bounds__(256) void embed_k(
    const float* __restrict__ el, const float* __restrict__ Win,
    const int* __restrict__ ip, const int* __restrict__ jp,
    ushort* __restrict__ h, int P0) {
    int w = threadIdx.x >> 6, lane = threadIdx.x & 63;
    int r = blockIdx.x * 4 + w;
    int gp = P0 + (r >> 1);
    int e = (r & 1) ? jp[gp] : ip[gp];
    float th = el[2 * e], ph = el[2 * e + 1];
    float st = sinf(th);
    float f0 = cosf(th), f1 = st * cosf(ph), f2 = st * sinf(ph);
    int n = lane * 4;
    float4 w0 = *(const float4*)&Win[n];
    float4 w1 = *(const float4*)&Win[256 + n];
    float4 w2 = *(const float4*)&Win[512 + n];
    ushort4 o;
    o.x = f2bf(f0 * w0.x + f1 * w1.x + f2 * w2.x);
    o.y = f2bf(f0 * w0.y + f1 * w1.y + f2 * w2.y);
    o.z = f2bf(f0 * w0.z + f1 * w1.z + f2 * w2.z);
    o.w = f2bf(f0 * w0.w + f1 * w1.w + f2 * w2.w);
    *(ushort4*)&h[(size_t)r * 256 + n] = o;
}

// ---------------- bf16 MFMA GEMM (128x128 tile, 256t): C = A@B (+bias) ----------------
template <bool BIAS>
__global__ __launch_bounds__(256) void gemm_k(
    const ushort* __restrict__ A, int lda,
    const ushort* __restrict__ Bt,
    const float* __restrict__ bias,
    ushort* __restrict__ C, int ldc) {
    __shared__ ushort As[128 * 64];
    __shared__ ushort Bs[128 * 64];
    int t = threadIdx.x, lane = t & 63, w = t >> 6;
    int row0 = blockIdx.x * 128, col0 = blockIdx.y * 128;
    int lrow = lane >> 3;
    int kx = ((lane & 7) ^ lrow) << 3;
    const ushort* gA = A + (size_t)(row0 + w * 32 + lrow) * lda + kx;
    const ushort* gB = Bt + (size_t)(col0 + w * 32 + lrow) * 256 + kx;
    f32x4 acc[4][4];
#pragma unroll
    for (int i = 0; i < 4; ++i)
#pragma unroll
        for (int j = 0; j < 4; ++j) acc[i][j] = (f32x4){0.f, 0.f, 0.f, 0.f};
    int wm = w >> 1, wn = w & 1;
    int mbase = wm * 64 + (lane & 15);
    int nbase = wn * 64 + (lane & 15);
    int l7 = lane & 7;
    for (int k0 = 0; k0 < 256; k0 += 64) {
        __syncthreads();
#pragma unroll
        for (int c2 = 0; c2 < 4; ++c2) {
            GLD16(gA + (size_t)(c2 * 8) * lda + k0, &As[(w * 4 + c2) * 512]);
            GLD16(gB + (size_t)(c2 * 8) * 256 + k0, &Bs[(w * 4 + c2) * 512]);
        }
        __syncthreads();
#pragma unroll
        for (int ks = 0; ks < 2; ++ks) {
            int kb = ks * 4 + (lane >> 4);
            bf16x8 af[4], bfr[4];
#pragma unroll
            for (int tm = 0; tm < 4; ++tm)
                af[tm] = *(const bf16x8*)&As[(mbase + tm * 16) * 64 + ((kb ^ l7) << 3)];
#pragma unroll
            for (int tn = 0; tn < 4; ++tn)
                bfr[tn] = *(const bf16x8*)&Bs[(nbase + tn * 16) * 64 + ((kb ^ l7) << 3)];
#pragma unroll
            for (int tm = 0; tm < 4; ++tm)
#pragma unroll
                for (int tn = 0; tn < 4; ++tn)
                    acc[tm][tn] = __builtin_amdgcn_mfma_f32_16x16x32_bf16(
                        af[tm], bfr[tn], acc[tm][tn], 0, 0, 0);
        }
    }
    int q = lane >> 4;
    int crow = row0 + wm * 64 + q * 4;
    int ccol = col0 + wn * 64 + (lane & 15);
#pragma unroll
    for (int tm = 0; tm < 4; ++tm)
#pragma unroll
        for (int r = 0; r < 4; ++r) {
            int row = crow + tm * 16 + r;
#pragma unroll
            for (int tn = 0; tn < 4; ++tn) {
                int col = ccol + tn * 16;
                float v = acc[tm][tn][r];
                if (BIAS) v += bias[col];
                C[(size_t)row * ldc + col] = f2bf(v);
            }
        }
}

// ---------------- fused GEMM + LayerNorm epilogue (128x256 tile, N=K=256) ----------
// VARIANT 0: out = LN(A@B + R)                (post-W1; R = residual, no bias)
// VARIANT 1: out = LN(A + tanh(A@B + bias))   (post-W2; A re-read as residual)
template <int VARIANT>
__global__ __launch_bounds__(256) void gemm_ln_k(
    const ushort* __restrict__ A, int lda,
    const ushort* __restrict__ Bt,
    const float* __restrict__ bias,
    const ushort* __restrict__ Rm,
    const float* __restrict__ sc, const float* __restrict__ bi,
    ushort* __restrict__ C) {
    __shared__ union {
        struct { ushort As[128 * 64]; ushort Bs[256 * 64]; } s;           // 48 KB
        struct { char pad[128 * 64 * 2]; float part[128][2][17][2]; } r;  // part overlays Bs
    } u;
    __shared__ float mv[128][2];
    int t = threadIdx.x, lane = t & 63, w = t >> 6;
    int row0 = blockIdx.x * 128;
    int lrow = lane >> 3;
    int kx = ((lane & 7) ^ lrow) << 3;
    const ushort* gA = A + (size_t)(row0 + w * 32 + lrow) * lda + kx;
    const ushort* gB = Bt + (size_t)(w * 64 + lrow) * 256 + kx;
    f32x4 acc[4][8];
#pragma unroll
    for (int i = 0; i < 4; ++i)
#pragma unroll
        for (int j = 0; j < 8; ++j) acc[i][j] = (f32x4){0.f, 0.f, 0.f, 0.f};
    int wm = w >> 1, wn = w & 1;
    int mbase = wm * 64 + (lane & 15);
    int nbase = wn * 128 + (lane & 15);
    int l7 = lane & 7;
    for (int k0 = 0; k0 < 256; k0 += 64) {
        __syncthreads();
#pragma unroll
        for (int c2 = 0; c2 < 4; ++c2)
            GLD16(gA + (size_t)(c2 * 8) * lda + k0, &u.s.As[(w * 4 + c2) * 512]);
#pragma unroll
        for (int c2 = 0; c2 < 8; ++c2)
            GLD16(gB + (size_t)(c2 * 8) * 256 + k0, &u.s.Bs[(w * 8 + c2) * 512]);
        __syncthreads();
#pragma unroll
        for (int ks = 0; ks < 2; ++ks) {
            int kb = ks * 4 + (lane >> 4);
            bf16x8 af[4], bfr[8];
#pragma unroll
            for (int tm = 0; tm < 4; ++tm)
                af[tm] = *(const bf16x8*)&u.s.As[(mbase + tm * 16) * 64 + ((kb ^ l7) << 3)];
#pragma unroll
            for (int tn = 0; tn < 8; ++tn)
                bfr[tn] = *(const bf16x8*)&u.s.Bs[(nbase + tn * 16) * 64 + ((kb ^ l7) << 3)];
#pragma unroll
            for (int tm = 0; tm < 4; ++tm)
#pragma unroll
                for (int tn = 0; tn < 8; ++tn)
                    acc[tm][tn] = __builtin_amdgcn_mfma_f32_16x16x32_bf16(
                        af[tm], bfr[tn], acc[tm][tn], 0, 0, 0);
        }
    }
    int q = lane >> 4, l15 = lane & 15;
    float bcol[8], scol[8], bicol[8];
#pragma unroll
    for (int tn = 0; tn < 8; ++tn) {
        int col = wn * 128 + tn * 16 + l15;
        bcol[tn] = (VARIANT == 1) ? bias[col] : 0.f;
        scol[tn] = sc[col];
        bicol[tn] = bi[col];
    }
    __syncthreads();  // done with As/Bs; part overlay begins
#pragma unroll
    for (int tm = 0; tm < 4; ++tm)
#pragma unroll
        for (int r = 0; r < 4; ++r) {
            int row_l = wm * 64 + tm * 16 + q * 4 + r;
            int row = row0 + row_l;
            float sum = 0.f, sq = 0.f;
#pragma unroll
            for (int tn = 0; tn < 8; ++tn) {
                int col = wn * 128 + tn * 16 + l15;
                float v = acc[tm][tn][r];
                if (VARIANT == 0) {
                    v += bf2f(Rm[(size_t)row * 256 + col]);
                } else {
                    v = bf2f(A[(size_t)row * lda + col]) + tanhf(v + bcol[tn]);
                }
                acc[tm][tn][r] = v;
                sum += v;
                sq += v * v;
            }
            *(float2*)&u.r.part[row_l][wn][l15][0] = make_float2(sum, sq);
        }
    __syncthreads();
    {
        int row = t >> 1, half = t & 1;
        float sum = 0.f, sq = 0.f;
#pragma unroll
        for (int i = 0; i < 16; ++i) {
            float2 pp = *(const float2*)&u.r.part[row][half][i][0];
            sum += pp.x;
            sq += pp.y;
        }
        sum += __shfl_xor(sum, 1, 64);
        sq += __shfl_xor(sq, 1, 64);
        if (half == 0) {
            float m = sum * (1.f / 256.f);
            float var = sq * (1.f / 256.f) - m * m;
            mv[row][0] = m;
            mv[row][1] = rsqrtf(var + 1e-5f);
        }
    }
    __syncthreads();
#pragma unroll
    for (int tm = 0; tm < 4; ++tm)
#pragma unroll
        for (int r = 0; r < 4; ++r) {
            int row_l = wm * 64 + tm * 16 + q * 4 + r;
            int row = row0 + row_l;
            float m = mv[row_l][0], rs = mv[row_l][1];
#pragma unroll
            for (int tn = 0; tn < 8; ++tn) {
                int col = wn * 128 + tn * 16 + l15;
                float v = (acc[tm][tn][r] - m) * rs * scol[tn] + bicol[tn];
                C[(size_t)row * 256 + col] = f2bf(v);
            }
        }
}

// ---------------- attention (seq=2) on fused qkv [row,768] ----------------
__global__ __launch_bounds__(256) void attn_k(ushort* __restrict__ qkv) {
    int wid = threadIdx.x >> 6, lane = threadIdx.x & 63;
    int gw = blockIdx.x * 4 + wid;
    int p = gw >> 2, hh = gw & 3;
    size_t r0 = (size_t)(2 * p) * 768 + hh * 64 + lane;
    size_t r1 = r0 + 768;
    float q0 = bf2f(qkv[r0]) * 0.125f, q1 = bf2f(qkv[r1]) * 0.125f;
    float k0 = bf2f(qkv[r0 + 256]), k1 = bf2f(qkv[r1 + 256]);
    float v0 = bf2f(qkv[r0 + 512]), v1 = bf2f(qkv[r1 + 512]);
    float s00 = q0 * k0, s01 = q0 * k1, s10 = q1 * k0, s11 = q1 * k1;
#pragma unroll
    for (int off = 32; off; off >>= 1) {
        s00 += __shfl_xor(s00, off, 64);
        s01 += __shfl_xor(s01, off, 64);
        s10 += __shfl_xor(s10, off, 64);
        s11 += __shfl_xor(s11, off, 64);
    }
    float m0 = fmaxf(s00, s01), m1 = fmaxf(s10, s11);
    float e00 = expf(s00 - m0), e01 = expf(s01 - m0);
    float e10 = expf(s10 - m1), e11 = expf(s11 - m1);
    float i0 = 1.f / (e00 + e01), i1 = 1.f / (e10 + e11);
    float o0 = (e00 * i0) * v0 + (e01 * i0) * v1;
    float o1 = (e10 * i1) * v0 + (e11 * i1) * v1;
    qkv[r0] = f2bf(o0);
    qkv[r1] = f2bf(o1);
}

// ---------------- per-pair orbitals + 2x2 det ----------------
__global__ __launch_bounds__(256) void orb_k(
    const ushort* __restrict__ h, const float* __restrict__ Wr, const float* __restrict__ Wi,
    const float* __restrict__ el, const int* __restrict__ ip, const int* __restrict__ jp,
    float2* __restrict__ porb, int P0) {
    int w = threadIdx.x >> 6, lane = threadIdx.x & 63;
    int p = blockIdx.x * 4 + w;
    const ushort* h0 = h + (size_t)(2 * p) * 256;
    int d0 = lane * 4;
    ushort4 a0 = *(const ushort4*)&h0[d0];
    ushort4 a1 = *(const ushort4*)&h0[256 + d0];
    float x0[4] = {bf2f(a0.x), bf2f(a0.y), bf2f(a0.z), bf2f(a0.w)};
    float x1[4] = {bf2f(a1.x), bf2f(a1.y), bf2f(a1.z), bf2f(a1.w)};
    float wrv[8], wiv[8];
    *(float4*)&wrv[0] = *(const float4*)&Wr[2 * d0];
    *(float4*)&wrv[4] = *(const float4*)&Wr[2 * d0 + 4];
    *(float4*)&wiv[0] = *(const float4*)&Wi[2 * d0];
    *(float4*)&wiv[4] = *(const float4*)&Wi[2 * d0 + 4];
    float s[8] = {0, 0, 0, 0, 0, 0, 0, 0};
#pragma unroll
    for (int u = 0; u < 4; ++u) {
        s[0] += x0[u] * wrv[2 * u];     s[1] += x0[u] * wiv[2 * u];
        s[2] += x0[u] * wrv[2 * u + 1]; s[3] += x0[u] * wiv[2 * u + 1];
        s[4] += x1[u] * wrv[2 * u];     s[5] += x1[u] * wiv[2 * u];
        s[6] += x1[u] * wrv[2 * u + 1]; s[7] += x1[u] * wiv[2 * u + 1];
    }
#pragma unroll
    for (int off = 32; off; off >>= 1) {
#pragma unroll
        for (int q2 = 0; q2 < 8; ++q2) s[q2] += __shfl_xor(s[q2], off, 64);
    }
    if (lane == 0) {
        int gp = P0 + p;
        int i = ip[gp], j = jp[gp];
        float thi = el[2 * i], phi_ = el[2 * i + 1];
        float thj = el[2 * j], phj = el[2 * j + 1];
        float chi = cosf(thi * 0.5f), shi = sinf(thi * 0.5f);
        float chj = cosf(thj * 0.5f), shj = sinf(thj * 0.5f);
        float cpi = cosf(phi_ * 0.5f), spi = sinf(phi_ * 0.5f);
        float cpj = cosf(phj * 0.5f), spj = sinf(phj * 0.5f);
        float uix = chi * cpi, uiy = chi * spi;
        float vix = shi * cpi, viy = -shi * spi;
        float ujx = chj * cpj, ujy = chj * spj;
        float vjx = shj * cpj, vjy = -shj * spj;
        float crx = (uix * vjx - uiy * vjy) - (ujx * vix - ujy * viy);
        float cry = (uix * vjy + uiy * vjx) - (ujx * viy + ujy * vix);
        float chord2 = crx * crx + cry * cry;
        float trunc = 1.f - expf(-100.f * chord2);
        float t2 = trunc * trunc;
        float dr = (s[0] * s[6] - s[1] * s[7]) - (s[2] * s[4] - s[3] * s[5]);
        float di = (s[0] * s[7] + s[1] * s[6]) - (s[2] * s[5] + s[3] * s[4]);
        porb[gp] = make_float2(dr * t2, di * t2);
    }
}

// ---------------- assemble A = pf + cusp, accumulate log_bos ----------------
__global__ __launch_bounds__(256) void assemble_k(
    const float* __restrict__ el, const float2* __restrict__ porb,
    float2* __restrict__ Am, float* acc) {
    __shared__ float sre[256], sim[256];
    int idx = blockIdx.x * 256 + threadIdx.x;
    int i = idx >> 8, j = idx & 255;
    float thi = el[2 * i], phi_ = el[2 * i + 1];
    float thj = el[2 * j], phj = el[2 * j + 1];
    float chi = cosf(thi * 0.5f), shi = sinf(thi * 0.5f);
    float chj = cosf(thj * 0.5f), shj = sinf(thj * 0.5f);
    float cpi = cosf(phi_ * 0.5f), spi = sinf(phi_ * 0.5f);
    float cpj = cosf(phj * 0.5f), spj = sinf(phj * 0.5f);
    float uix = chi * cpi, uiy = chi * spi;
    float vix = shi * cpi, viy = -shi * spi;
    float ujx = chj * cpj, ujy = chj * spj;
    float vjx = shj * cpj, vjy = -shj * spj;
    float ex = (uix * vjx - uiy * vjy) - (ujx * vix - ujy * viy);
    float ey = (uix * vjy + uiy * vjx) - (ujx * viy + ujy * vix);
    float pfx = 0.f, pfy = 0.f;
    if (i < j) {
        int pp = i * 255 - (i * (i - 1)) / 2 + (j - i - 1);
        float2 t = porb[pp]; pfx = t.x; pfy = t.y;
    } else if (i > j) {
        int pp = j * 255 - (j * (j - 1)) / 2 + (i - j - 1);
        float2 t = porb[pp]; pfx = -t.x; pfy = -t.y;
    }
    float eye = (i == j) ? 1.f : 0.f;
    float ecx = ex + eye, ecy = ey;
    float wgt = expf(-100.f * (ecx * ecx + ecy * ecy));
    Am[idx] = make_float2(pfx + ecx * wgt, pfy + ecy * wgt);
    float lre = 0.f, lim = 0.f;
    if (i != j) {
        float r2 = ex * ex + ey * ey;
        lre = 0.5f * logf(0.01f + r2);
        lim = atan2f(ey, ex);
    }
    sre[threadIdx.x] = lre; sim[threadIdx.x] = lim;
    __syncthreads();
    for (int s2 = 128; s2; s2 >>= 1) {
        if (threadIdx.x < s2) {
            sre[threadIdx.x] += sre[threadIdx.x + s2];
            sim[threadIdx.x] += sim[threadIdx.x + s2];
        }
        __syncthreads();
    }
    if (threadIdx.x == 0) {
        atomicAdd(acc + 0, sre[0]);
        atomicAdd(acc + 1, sim[0]);
    }
}

// ---------------- LU panel v7: register rows + DPP argmax ----------------
__global__ __launch_bounds__(256, 1) void panel_k(
    float2* __restrict__ Am, int* __restrict__ pivg, float* __restrict__ acc, int k0) {
    __shared__ unsigned wmax[4];
    __shared__ float2 urow_s[NB];
    __shared__ float2 rowj_s[NB];
    __shared__ float2 diag_s[NB];
    int t = threadIdx.x, lane = t & 63, w = t >> 6;
    int nr = NE - k0;
    bool act = t < nr;
    float2 a[NB];
    if (act) {
        const float2* src = Am + (size_t)(k0 + t) * NE + k0;
#pragma unroll
        for (int c = 0; c < NB; ++c) a[c] = src[c];
    }
    unsigned key = 0u;
    if (act) {
        float v = fabsf(a[0].x) + fabsf(a[0].y);
        key = (__float_as_uint(v) & 0xFFFFFF00u) | (unsigned)t;
    }
    int nsw = 0;
#pragma unroll
    for (int j = 0; j < NB; ++j) {
        unsigned mk = dpp_wave_max(key);   // VALU-speed, uniform per wave
        if (lane == 0) wmax[w] = mk;
        __syncthreads();
        mk = max(max(wmax[0], wmax[1]), max(wmax[2], wmax[3]));
        int piv = (int)(mk & 0xFFu);
        if (t == piv) {
#pragma unroll
            for (int c = 0; c < NB; ++c) urow_s[c] = a[c];
        }
        if (t == j && j != piv) {
#pragma unroll
            for (int c = 0; c < NB; ++c) rowj_s[c] = a[c];
        }
        if (t == 0) {
            pivg[j] = k0 + piv;
            if (piv != j) nsw++;
        }
        __syncthreads();
        float2 uu[NB];
#pragma unroll
        for (int c = j; c < NB; ++c) uu[c] = urow_s[c];
        float2 d = uu[j];
        if (t == 0) diag_s[j] = d;
        float ivn = 1.f / (d.x * d.x + d.y * d.y);
        float2 inv = make_float2(d.x * ivn, -d.y * ivn);
        if (t == j) {
#pragma unroll
            for (int c = j; c < NB; ++c) a[c] = uu[c];
#pragma unroll
            for (int c = 0; c < j; ++c) a[c] = urow_s[c];
        } else if (t == piv) {
#pragma unroll
            for (int c = 0; c < NB; ++c) a[c] = rowj_s[c];
        }
        key = 0u;
        if (act && t > j) {
            float2 L = make_float2(a[j].x * inv.x - a[j].y * inv.y,
                                   a[j].x * inv.y + a[j].y * inv.x);
            a[j] = L;
#pragma unroll
            for (int c = j + 1; c < NB; ++c) {
                a[c].x -= L.x * uu[c].x - L.y * uu[c].y;
                a[c].y -= L.x * uu[c].y + L.y * uu[c].x;
            }
            if (j + 1 < NB) {
                float v = fabsf(a[j + 1].x) + fabsf(a[j + 1].y);
                key = (__float_as_uint(v) & 0xFFFFFF00u) | (unsigned)t;
            }
        }
    }
    if (act) {
        float2* dst = Am + (size_t)(k0 + t) * NE + k0;
#pragma unroll
        for (int c = 0; c < NB; ++c) dst[c] = a[c];
    }
    __syncthreads();
    if (w == 0) {
        float lre = 0.f, lim = 0.f;
        if (lane < NB) {
            float2 d = diag_s[lane];
            lre = 0.5f * logf(d.x * d.x + d.y * d.y);
            lim = atan2f(d.y, d.x);
        }
#pragma unroll
        for (int off = 32; off; off >>= 1) {
            lre += __shfl_xor(lre, off, 64);
            lim += __shfl_xor(lim, off, 64);
        }
        if (lane == 0) { acc[2] += lre; acc[3] += lim; }
    }
    if (t == 0) acc[4] += (float)nsw;
}

// ---------------- trsm: composed-permutation gather + register solve ----------------
__global__ __launch_bounds__(256) void trsm_k(
    float2* __restrict__ Am, const int* __restrict__ pivg, int k0) {
    __shared__ float2 Ls[NB][NB + 1];
    __shared__ short sigma[NE];
    __shared__ short rlist[NB];
    __shared__ int rcount;
    int t = threadIdx.x;
    for (int idx = t; idx < NB * NB; idx += 256)
        Ls[idx >> 5][idx & 31] = Am[(size_t)(k0 + (idx >> 5)) * NE + k0 + (idx & 31)];
    {   // parallel sigma: replay swaps backward on own index
        int x = t;
#pragma unroll
        for (int j = NB - 1; j >= 0; --j) {
            int pj = pivg[j], rj = k0 + j;
            x = (x == rj) ? pj : ((x == pj) ? rj : x);
        }
        sigma[t] = (short)x;
    }
    if (t < NB) rlist[t] = (short)k0;  // dummy default (valid row, never stored)
    if (t == 0) rcount = 0;
    __syncthreads();
    if (t >= k0 + NB && sigma[t] != t) {
        int s = atomicAdd(&rcount, 1);
        rlist[s] = (short)t;
    }
    __syncthreads();
    int ncols = NE - k0 - NB;
    if (t >= ncols) return;
    int col = k0 + NB + t;
    int cnt = rcount;
    float2 x[NB];
#pragma unroll
    for (int i = 0; i < NB; ++i)
        x[i] = Am[(size_t)sigma[k0 + i] * NE + col];
    float2 extra[NB];
#pragma unroll
    for (int q = 0; q < NB; ++q)
        extra[q] = Am[(size_t)sigma[rlist[q]] * NE + col];
#pragma unroll
    for (int i = 1; i < NB; ++i) {
        float2 xi = x[i];
#pragma unroll
        for (int j = 0; j < i; ++j) {
            float2 l = Ls[i][j];
            xi.x -= l.x * x[j].x - l.y * x[j].y;
            xi.y -= l.x * x[j].y + l.y * x[j].x;
        }
        x[i] = xi;
    }
#pragma unroll
    for (int i = 0; i < NB; ++i)
        Am[(size_t)(k0 + i) * NE + col] = x[i];
#pragma unroll
    for (int q = 0; q < NB; ++q)
        if (q < cnt) Am[(size_t)rlist[q] * NE + col] = extra[q];
}

// A22 -= L21 @ U12, complex, K=NB. 32x32 tile per block.
__global__ __launch_bounds__(256) void update_k(float2* __restrict__ Am, int k0) {
    __shared__ float2 Lt[NB][NB + 1];
    __shared__ float2 Ut[NB][NB + 1];
    int t = threadIdx.x;
    int r0 = k0 + NB + blockIdx.x * NB;
    int c0 = k0 + NB + blockIdx.y * NB;
    for (int idx = t; idx < NB * NB; idx += 256) {
        int a = idx >> 5, b = idx & 31;
        Lt[a][b] = Am[(size_t)(r0 + a) * NE + k0 + b];
        Ut[a][b] = Am[(size_t)(k0 + a) * NE + c0 + b];
    }
    __syncthreads();
    int lr = t >> 3, lc0 = (t & 7) * 4;
    float2 s0 = {0.f, 0.f}, s1 = {0.f, 0.f}, s2 = {0.f, 0.f}, s3 = {0.f, 0.f};
#pragma unroll
    for (int k = 0; k < NB; ++k) {
        float2 a = Lt[lr][k];
        float2 u0 = Ut[k][lc0 + 0], u1 = Ut[k][lc0 + 1];
        float2 u2 = Ut[k][lc0 + 2], u3 = Ut[k][lc0 + 3];
        s0.x += a.x * u0.x - a.y * u0.y; s0.y += a.x * u0.y + a.y * u0.x;
        s1.x += a.x * u1.x - a.y * u1.y; s1.y += a.x * u1.y + a.y * u1.x;
        s2.x += a.x * u2.x - a.y * u2.y; s2.y += a.x * u2.y + a.y * u2.x;
        s3.x += a.x * u3.x - a.y * u3.y; s3.y += a.x * u3.y + a.y * u3.x;
    }
    size_t base = (size_t)(r0 + lr) * NE + c0 + lc0;
    float2 cc;
    cc = Am[base + 0]; cc.x -= s0.x; cc.y -= s0.y; Am[base + 0] = cc;
    cc = Am[base + 1]; cc.x -= s1.x; cc.y -= s1.y; Am[base + 1] = cc;
    cc = Am[base + 2]; cc.x -= s2.x; cc.y -= s2.y; Am[base + 2] = cc;
    cc = Am[base + 3]; cc.x -= s3.x; cc.y -= s3.y; Am[base + 3] = cc;
}

__global__ void finalize_k(const float* __restrict__ acc, float* __restrict__ out) {
    if (threadIdx.x == 0) {
        float ang = acc[3] + 3.14159265358979323846f * acc[4];
        ang -= 6.283185307179586f * rintf(ang * 0.15915494309189535f);
        out[0] = 0.5f * acc[2] + acc[0];
        out[1] = 0.5f * ang + acc[1];
    }
}

// ---------------- host launch ----------------
extern "C" void kernel_launch(void* const* d_in, const int* in_sizes, int n_in,
                              void* d_out, int out_size, void* d_ws, size_t ws_size,
                              hipStream_t stream) {
    (void)in_sizes; (void)n_in; (void)out_size;
    const float* el   = (const float*)d_in[0];
    const float* Win  = (const float*)d_in[1];
    const float* Wq   = (const float*)d_in[2];
    const float* bq   = (const float*)d_in[3];
    const float* Wk   = (const float*)d_in[4];
    const float* bk   = (const float*)d_in[5];
    const float* Wv   = (const float*)d_in[6];
    const float* bv   = (const float*)d_in[7];
    const float* Wo   = (const float*)d_in[8];
    const float* bo   = (const float*)d_in[9];
    const float* W1   = (const float*)d_in[10];
    const float* ln1s = (const float*)d_in[11];
    const float* ln1b = (const float*)d_in[12];
    const float* W2   = (const float*)d_in[13];
    const float* b2   = (const float*)d_in[14];
    const float* ln2s = (const float*)d_in[15];
    const float* ln2b = (const float*)d_in[16];
    const float* Wor  = (const float*)d_in[17];
    const float* Woi  = (const float*)d_in[18];

    char* wp = (char*)d_ws;
    auto alloc = [&](size_t b) {
        char* r = wp;
        wp += (b + 255) & ~(size_t)255;
        return r;
    };
    int*    ipb  = (int*)alloc((size_t)P_TOT * 4);
    int*    jpb  = (int*)alloc((size_t)P_TOT * 4);
    float2* porb = (float2*)alloc((size_t)P_TOT * 8);
    float2* Am   = (float2*)alloc((size_t)NE * NE * 8);
    float*  acc  = (float*)alloc(256);
    int*    pivg = (int*)alloc((size_t)NE * 4);
    ushort* Wqkv_t = (ushort*)alloc((size_t)2 * 768 * 256 * 2);
    ushort* Woth_t = (ushort*)alloc((size_t)6 * 65536 * 2);
    float*  bqkv = (float*)alloc((size_t)2 * 768 * 4);
    ushort* hb   = (ushort*)alloc((size_t)MC * 256 * 2);
    ushort* qkvb = (ushort*)alloc((size_t)MC * 768 * 2);
    ushort* tb   = (ushort*)alloc((size_t)MC * 256 * 2);
    size_t need = (size_t)(wp - (char*)d_ws);
    if (need > ws_size) {
        zero_k<<<1, 64, 0, stream>>>((float*)d_out);
        return;
    }

    prep_w_k<<<dim3(8, 8, 12), 256, 0, stream>>>(Wq, Wk, Wv, Wo, W1, W2, Wqkv_t, Woth_t);
    prep_misc_k<<<1, 256, 0, stream>>>(ipb, jpb, acc, bq, bk, bv, bqkv);

    for (int c = 0; c < NCHUNK; ++c) {
        int P0 = c * PC;
        embed_k<<<MC / 4, 256, 0, stream>>>(el, Win, ipb, jpb, hb, P0);
        for (int l = 0; l < NL; ++l) {
            gemm_k<true><<<dim3(MT, 6), 256, 0, stream>>>(
                hb, 256, Wqkv_t + (size_t)l * 768 * 256, bqkv + l * 768, qkvb, 768);
            attn_k<<<PC, 256, 0, stream>>>(qkvb);
            gemm_k<true><<<dim3(MT, 2), 256, 0, stream>>>(
                qkvb, 768, Woth_t + (size_t)(l * 3 + 0) * 65536, bo + l * 256, tb, 256);
            gemm_ln_k<0><<<MT, 256, 0, stream>>>(
                tb, 256, Woth_t + (size_t)(l * 3 + 1) * 65536, nullptr, hb,
                ln1s + l * 256, ln1b + l * 256, hb);
            gemm_ln_k<1><<<MT, 256, 0, stream>>>(
                hb, 256, Woth_t + (size_t)(l * 3 + 2) * 65536, b2 + l * 256, nullptr,
                ln2s + l * 256, ln2b + l * 256, hb);
        }
        orb_k<<<PC / 4, 256, 0, stream>>>(hb, Wor, Woi, el, ipb, jpb, porb, P0);
    }
    assemble_k<<<NE, 256, 0, stream>>>(el, porb, Am, acc);

    for (int p = 0; p < NPANEL; ++p) {
        int k0 = p * NB;
        panel_k<<<1, 256, 0, stream>>>(Am, pivg + p * NB, acc, k0);
        int m = NE - k0 - NB;
        if (m > 0) {
            trsm_k<<<1, 256, 0, stream>>>(Am, pivg + p * NB, k0);
            dim3 ug(m / NB, m / NB);
            update_k<<<ug, 256, 0, stream>>>(Am, k0);
        }
    }
    finalize_k<<<1, 64, 0, stream>>>(acc, (float*)d_out);
}